// Round 9
// baseline (202.346 us; speedup 1.0000x reference)
//
#include <hip/hip_runtime.h>
#include <hip/hip_bf16.h>
#include <stdint.h>

// B=2, S=2048, D=1024, H=16, Hd=64.  Inputs/outputs FP32; internal bf16 MFMA.
// R9 = R8 with the K-loops restructured to double-buffered single-barrier
// pipelines: stage tile i+1 right after the barrier that opens compute on
// tile i -> the vmcnt drain at the next barrier covers a prefetch that had a
// full compute phase to land (R8's 2-barrier loop exposed staging latency on
// every one of 32 iterations; counters showed 56us vs ~34us of busiest-pipe
// work).  Attn compute body, P-path, XCD swizzle unchanged from R8 (56.3us).

typedef __bf16 bf16;
typedef __attribute__((ext_vector_type(8))) __bf16 bf16x8;
typedef __attribute__((ext_vector_type(4))) __bf16 bf16x4;
typedef __attribute__((ext_vector_type(4))) float f32x4;

#define DEVI __device__ __forceinline__

DEVI void gl_lds16(const void* g, void* l) {
  __builtin_amdgcn_global_load_lds(
      (const __attribute__((address_space(1))) void*)g,
      (__attribute__((address_space(3))) void*)l, 16, 0, 0);
}

DEVI bf16x8 load8(const bf16* p) { return *(const bf16x8*)p; }
DEVI bf16x8 load8(const float* p) {
  f32x4 a = *(const f32x4*)p;
  f32x4 b = *(const f32x4*)(p + 4);
  bf16x8 r;
  r[0] = (bf16)a[0]; r[1] = (bf16)a[1]; r[2] = (bf16)a[2]; r[3] = (bf16)a[3];
  r[4] = (bf16)b[0]; r[5] = (bf16)b[1]; r[6] = (bf16)b[2]; r[7] = (bf16)b[3];
  return r;
}

// ---------------------------------------------------------------------------
// fp32 -> bf16 bulk convert.  grid (512, 8): y<4 -> W[y], y>=4 -> x quarter.
// ---------------------------------------------------------------------------
__global__ __launch_bounds__(256)
void cvt_kernel(const float* __restrict__ x,
                const float* __restrict__ w0, const float* __restrict__ w1,
                const float* __restrict__ w2, const float* __restrict__ w3,
                bf16* __restrict__ xb, bf16* __restrict__ wb) {
  const int y = blockIdx.y;
  const float* src;
  bf16* dst;
  if (y < 4) {
    src = (y == 0) ? w0 : (y == 1) ? w1 : (y == 2) ? w2 : w3;
    dst = wb + (size_t)y * 1048576;
  } else {
    src = x + (size_t)(y - 4) * 1048576;
    dst = xb + (size_t)(y - 4) * 1048576;
  }
  const int i = (blockIdx.x * 256 + threadIdx.x) * 8;
  *(bf16x8*)(dst + i) = load8(src + i);
}

// ---------------------------------------------------------------------------
// GEMM: C[m,n] = (sum_k X[m,k] * W[n,k]) * scale[n] [* emul], M=4096, K=1024.
// bf16/bf16: double-buffered async staging, ONE barrier per K-tile.
// Other dtypes (fallback only): R6 two-barrier manual path on buffer 0.
// three=1 (NTILE=128): 8 n-tiles per W; Q/K -> [B,H,S,64] (Q gets
//   emul=0.125*log2e), V -> transposed [B,H,64,S].
// three=0 (NTILE=64): plain fp32 row-major out.
// ---------------------------------------------------------------------------
template <typename XT, typename WT, int NTILE>
__global__ __launch_bounds__(256, 2)
void gemm_kernel(const XT* __restrict__ X,
                 const WT* __restrict__ W0, const WT* __restrict__ W1,
                 const WT* __restrict__ W2,
                 const float* __restrict__ s0, const float* __restrict__ s1,
                 const float* __restrict__ s2,
                 bf16* __restrict__ o0, bf16* __restrict__ o1,
                 bf16* __restrict__ o2, float* __restrict__ ofp, int three) {
  constexpr int NF = NTILE / 32;
  constexpr bool ASYNC = (sizeof(XT) == 2) && (sizeof(WT) == 2);
  __shared__ bf16 As[2][128 * 32];
  __shared__ bf16 Bs[2][NTILE * 32];

  const int t = threadIdx.x;
  const int lane = t & 63;
  const int w = t >> 6;
  const int wm = w >> 1, wn = w & 1;
  const int m0 = blockIdx.x * 128;
  const int cl = lane & 15, quad = lane >> 4;

  const WT* Wp; const float* sp; bf16* op; int mode, n0; float emul = 1.f;
  if (three) {
    int which = blockIdx.y >> 3;
    n0 = (blockIdx.y & 7) * 128;
    if (which == 0)      { Wp = W0; sp = s0; op = o0; mode = 1; emul = 0.18033688f; }
    else if (which == 1) { Wp = W1; sp = s1; op = o1; mode = 1; }
    else                 { Wp = W2; sp = s2; op = o2; mode = 2; }
  } else {
    n0 = blockIdx.y * NTILE; Wp = W0; sp = s0; op = o0; mode = 0;
  }

  f32x4 zero = {0.f, 0.f, 0.f, 0.f};
  f32x4 acc[4][NF];
#pragma unroll
  for (int i = 0; i < 4; i++)
#pragma unroll
    for (int j = 0; j < NF; j++) acc[i][j] = zero;

  const int srow = t >> 2;
  const int gcol_sw = ((t & 3) ^ (srow & 3)) * 8;
  const int gcol = (t & 3) * 8;
  const int sphys = (((t & 3) ^ (srow & 3)) << 3);

#define STAGEG(bi, k0_)                                                        \
  {                                                                            \
    gl_lds16(X + (uint64_t)(m0 + srow) * 1024 + (k0_) + gcol_sw,               \
             (char*)As[bi] + t * 16);                                          \
    gl_lds16(X + (uint64_t)(m0 + 64 + srow) * 1024 + (k0_) + gcol_sw,          \
             (char*)As[bi] + 4096 + t * 16);                                   \
    gl_lds16(Wp + (uint64_t)(n0 + srow) * 1024 + (k0_) + gcol_sw,              \
             (char*)Bs[bi] + t * 16);                                          \
    if (NTILE == 128)                                                          \
      gl_lds16(Wp + (uint64_t)(n0 + 64 + srow) * 1024 + (k0_) + gcol_sw,       \
               (char*)Bs[bi] + 4096 + t * 16);                                 \
  }

  if constexpr (ASYNC) {
    STAGEG(0, 0)
    for (int it = 0; it < 32; it++) {
      __syncthreads();   // own prefetch (vmcnt) drained; all waves off prev buf
      if (it < 31) STAGEG((it + 1) & 1, (it + 1) * 32)
      const bf16* Ab = As[it & 1];
      const bf16* Bb = Bs[it & 1];

      bf16x8 af[4], bfr[NF];
#pragma unroll
      for (int mt = 0; mt < 4; mt++) {
        const int row = wm * 64 + mt * 16 + cl;
        af[mt] = *(const bf16x8*)&Ab[row * 32 + ((quad ^ (cl & 3)) << 3)];
      }
#pragma unroll
      for (int nt = 0; nt < NF; nt++) {
        const int row = wn * (NF * 16) + nt * 16 + cl;
        bfr[nt] = *(const bf16x8*)&Bb[row * 32 + ((quad ^ (cl & 3)) << 3)];
      }
#pragma unroll
      for (int mt = 0; mt < 4; mt++)
#pragma unroll
        for (int nt = 0; nt < NF; nt++)
          acc[mt][nt] = __builtin_amdgcn_mfma_f32_16x16x32_bf16(
              af[mt], bfr[nt], acc[mt][nt], 0, 0, 0);
    }
  } else {
    for (int k0 = 0; k0 < 1024; k0 += 32) {
      bf16x8 a0 = load8(&X[(uint64_t)(m0 + srow) * 1024 + k0 + gcol]);
      bf16x8 a1 = load8(&X[(uint64_t)(m0 + 64 + srow) * 1024 + k0 + gcol]);
      bf16x8 b0 = load8(&Wp[(uint64_t)(n0 + srow) * 1024 + k0 + gcol]);
      bf16x8 b1;
      if (NTILE == 128)
        b1 = load8(&Wp[(uint64_t)(n0 + 64 + srow) * 1024 + k0 + gcol]);
      __syncthreads();
      *(bf16x8*)&As[0][srow * 32 + sphys] = a0;
      *(bf16x8*)&As[0][(64 + srow) * 32 + sphys] = a1;
      *(bf16x8*)&Bs[0][srow * 32 + sphys] = b0;
      if (NTILE == 128)
        *(bf16x8*)&Bs[0][(64 + srow) * 32 + sphys] = b1;
      __syncthreads();

      bf16x8 af[4], bfr[NF];
#pragma unroll
      for (int mt = 0; mt < 4; mt++) {
        const int row = wm * 64 + mt * 16 + cl;
        af[mt] = *(const bf16x8*)&As[0][row * 32 + ((quad ^ (cl & 3)) << 3)];
      }
#pragma unroll
      for (int nt = 0; nt < NF; nt++) {
        const int row = wn * (NF * 16) + nt * 16 + cl;
        bfr[nt] = *(const bf16x8*)&Bs[0][row * 32 + ((quad ^ (cl & 3)) << 3)];
      }
#pragma unroll
      for (int mt = 0; mt < 4; mt++)
#pragma unroll
        for (int nt = 0; nt < NF; nt++)
          acc[mt][nt] = __builtin_amdgcn_mfma_f32_16x16x32_bf16(
              af[mt], bfr[nt], acc[mt][nt], 0, 0, 0);
    }
  }
#undef STAGEG

#pragma unroll
  for (int nt = 0; nt < NF; nt++) {
    const int gn = n0 + wn * (NF * 16) + nt * 16 + cl;
    const float sc = sp[gn] * emul;
#pragma unroll
    for (int mt = 0; mt < 4; mt++) {
      const int gmb = m0 + wm * 64 + mt * 16 + quad * 4;
#pragma unroll
      for (int r = 0; r < 4; r++) {
        const int gm = gmb + r;
        const float v = acc[mt][nt][r] * sc;
        if (mode == 0) {
          ofp[(uint64_t)gm * 1024 + gn] = v;
        } else {
          const int b = gm >> 11, s = gm & 2047;
          const int h = gn >> 6, hd = gn & 63;
          uint64_t addr;
          if (mode == 1) addr = ((uint64_t)(b * 16 + h) * 2048 + s) * 64 + hd;
          else           addr = ((uint64_t)(b * 16 + h) * 64 + hd) * 2048 + s;
          op[addr] = (bf16)v;
        }
      }
    }
  }
}

// ---------------------------------------------------------------------------
// Flash attention (R8 compute body), double-buffered K/V staging, ONE barrier
// per 64-key tile.  1D grid 512 blocks, XCD-swizzled: xcd=id&7, k=id>>3,
// bh=xcd*4+(k>>4), qt=k&15.  Block = 128 q-rows, 4 waves, wave w owns rows
// {q0+mt*64+w*16+[0,16)}.  S^T = mfma(A=Kfrag, B=Qfrag); exp2 -> bf16x4 ->
// b64 write into swizzled P[query][key] -> b128 A-frags for PV.
// ---------------------------------------------------------------------------
__global__ __launch_bounds__(256, 2)
void attn_kernel(const bf16* __restrict__ Qw, const bf16* __restrict__ Kw,
                 const bf16* __restrict__ Vtw, bf16* __restrict__ Ctx) {
  __shared__ bf16 Ks[2][64 * 64];       // [key][d], swizzled      (16 KB)
  __shared__ bf16 Vs[2][64 * 64];       // [hd][key], swizzled     (16 KB)
  __shared__ bf16 Ps[8 * 16 * 64];      // [w*2+mt][query][key]    (16 KB)

  const int t = threadIdx.x, lane = t & 63, w = t >> 6;
  const int cl = lane & 15, quad = lane >> 4;

  const int id = blockIdx.x;
  const int xcd = id & 7, k = id >> 3;
  const int bh = xcd * 4 + (k >> 4);
  const int qt = k & 15;
  const int b = bh >> 4, h = bh & 15;
  const int q0 = qt * 128;

  const bf16* Qh = Qw + (uint64_t)bh * 2048 * 64;
  const bf16* Kh = Kw + (uint64_t)bh * 2048 * 64;
  const bf16* Vh = Vtw + (uint64_t)bh * 64 * 2048;

  // Q B-fragments: B[k=quad*8+j][n=lane&15]
  bf16x8 qf[2][2];
#pragma unroll
  for (int mt = 0; mt < 2; mt++) {
    const int r = q0 + mt * 64 + w * 16 + cl;
    qf[mt][0] = *(const bf16x8*)&Qh[(uint64_t)r * 64 + quad * 8];
    qf[mt][1] = *(const bf16x8*)&Qh[(uint64_t)r * 64 + 32 + quad * 8];
  }

  f32x4 zero = {0.f, 0.f, 0.f, 0.f};
  f32x4 o_acc[2][4];
  float lsum[2] = {0.f, 0.f};
#pragma unroll
  for (int mt = 0; mt < 2; mt++)
#pragma unroll
    for (int i = 0; i < 4; i++) o_acc[mt][i] = zero;

  const int srow = t >> 3;                         // 0..31
  const int gcol_sw = ((t & 7) ^ (srow & 7)) * 8;  // swizzled source col
  const int psw = (cl & 7) << 1;                   // P chunk swizzle

#define STAGEA(bi, k0_)                                                        \
  {                                                                            \
    gl_lds16(Kh + (uint64_t)((k0_) + srow) * 64 + gcol_sw,                     \
             (char*)Ks[bi] + t * 16);                                          \
    gl_lds16(Kh + (uint64_t)((k0_) + 32 + srow) * 64 + gcol_sw,                \
             (char*)Ks[bi] + 4096 + t * 16);                                   \
    gl_lds16(Vh + (uint64_t)srow * 2048 + (k0_) + gcol_sw,                     \
             (char*)Vs[bi] + t * 16);                                          \
    gl_lds16(Vh + (uint64_t)(32 + srow) * 2048 + (k0_) + gcol_sw,              \
             (char*)Vs[bi] + 4096 + t * 16);                                   \
  }

  STAGEA(0, 0)

  for (int it = 0; it < 32; it++) {
    __syncthreads();   // own prefetch drained; all waves done with prev buf
    if (it < 31) STAGEA((it + 1) & 1, (it + 1) * 64)
    const bf16* Ksb = Ks[it & 1];
    const bf16* Vsb = Vs[it & 1];

    // S^T (log2 units): lane holds keys nt*16+quad*4+reg, query cl
#pragma unroll
    for (int nt = 0; nt < 4; nt++) {
      const int krow = nt * 16 + cl;
      bf16x8 kf0 = *(const bf16x8*)&Ksb[krow * 64 + ((quad ^ (cl & 7)) << 3)];
      bf16x8 kf1 = *(const bf16x8*)&Ksb[krow * 64 + (((quad + 4) ^ (cl & 7)) << 3)];
#pragma unroll
      for (int mt = 0; mt < 2; mt++) {
        f32x4 s = __builtin_amdgcn_mfma_f32_16x16x32_bf16(kf0, qf[mt][0], zero, 0, 0, 0);
        s = __builtin_amdgcn_mfma_f32_16x16x32_bf16(kf1, qf[mt][1], s, 0, 0, 0);
        bf16x4 pk;
        float ls = 0.f;
#pragma unroll
        for (int r = 0; r < 4; r++) {
          const float p = __builtin_amdgcn_exp2f(s[r]);
          ls += p;
          pk[r] = (bf16)p;
        }
        lsum[mt] += ls;
        bf16* Pm = Ps + (w * 2 + mt) * 1024;
        const int c = 4 * nt + quad;
        *(bf16x4*)&Pm[cl * 64 + ((c ^ psw) << 2)] = pk;
      }
    }

    // P A-frags: lane(cl,quad) reads keys 32h+8*quad+[0,8) of query cl
    bf16x8 pf[2][2];
#pragma unroll
    for (int mt = 0; mt < 2; mt++) {
      const bf16* Pm = Ps + (w * 2 + mt) * 1024;
#pragma unroll
      for (int hh = 0; hh < 2; hh++) {
        const int c0 = 8 * hh + 2 * quad;
        pf[mt][hh] = *(const bf16x8*)&Pm[cl * 64 + ((c0 ^ psw) << 2)];
      }
    }

    // PV: O[query][hd] += P * V
#pragma unroll
    for (int nt = 0; nt < 4; nt++) {
      const int vrow = nt * 16 + cl;
      bf16x8 v0 = *(const bf16x8*)&Vsb[vrow * 64 + ((quad ^ (cl & 7)) << 3)];
      bf16x8 v1 = *(const bf16x8*)&Vsb[vrow * 64 + (((quad + 4) ^ (cl & 7)) << 3)];
#pragma unroll
      for (int mt = 0; mt < 2; mt++) {
        o_acc[mt][nt] = __builtin_amdgcn_mfma_f32_16x16x32_bf16(pf[mt][0], v0,
                                                                o_acc[mt][nt], 0, 0, 0);
        o_acc[mt][nt] = __builtin_amdgcn_mfma_f32_16x16x32_bf16(pf[mt][1], v1,
                                                                o_acc[mt][nt], 0, 0, 0);
      }
    }
  }
#undef STAGEA

  // epilogue: reduce l across quads, then O/l
  float linv[2][4];
#pragma unroll
  for (int mt = 0; mt < 2; mt++) {
    float l = lsum[mt];
    l += __shfl_xor(l, 16);
    l += __shfl_xor(l, 32);
#pragma unroll
    for (int r = 0; r < 4; r++)
      linv[mt][r] = 1.0f / __shfl(l, quad * 4 + r);
  }
#pragma unroll
  for (int mt = 0; mt < 2; mt++)
#pragma unroll
    for (int nt = 0; nt < 4; nt++)
#pragma unroll
      for (int r = 0; r < 4; r++) {
        const int s = q0 + mt * 64 + w * 16 + quad * 4 + r;
        const int hd = nt * 16 + cl;
        Ctx[(uint64_t)(b * 2048 + s) * 1024 + h * 64 + hd] =
            (bf16)(o_acc[mt][nt][r] * linv[mt][r]);
      }
}

// ---------------------------------------------------------------------------
extern "C" void kernel_launch(void* const* d_in, const int* in_sizes, int n_in,
                              void* d_out, int out_size, void* d_ws, size_t ws_size,
                              hipStream_t stream) {
  const float* x  = (const float*)d_in[0];
  const float* Wq = (const float*)d_in[1];
  const float* Wk = (const float*)d_in[2];
  const float* Wv = (const float*)d_in[3];
  const float* Wo = (const float*)d_in[4];
  const float* qs = (const float*)d_in[5];
  const float* ks = (const float*)d_in[6];
  const float* vs = (const float*)d_in[7];
  const float* os = (const float*)d_in[8];
  float* out = (float*)d_out;

  const size_t M4 = 4194304, M1 = 1048576;

  if (ws_size >= (size_t)40 * 1024 * 1024) {
    bf16* xb = (bf16*)d_ws;        // 4M bf16; reused as cw after QKV
    bf16* wb = xb + M4;            // wq|wk|wv|wo
    bf16* qw = wb + M4;
    bf16* kw = qw + M4;
    bf16* vw = kw + M4;
    bf16* cw = xb;

    cvt_kernel<<<dim3(512, 8), 256, 0, stream>>>(x, Wq, Wk, Wv, Wo, xb, wb);
    gemm_kernel<bf16, bf16, 128><<<dim3(32, 24), 256, 0, stream>>>(
        xb, wb, wb + M1, wb + 2 * M1, qs, ks, vs, qw, kw, vw, nullptr, 1);
    attn_kernel<<<512, 256, 0, stream>>>(qw, kw, vw, cw);
    gemm_kernel<bf16, bf16, 64><<<dim3(32, 16), 256, 0, stream>>>(
        cw, wb + 3 * M1, nullptr, nullptr, os, nullptr, nullptr,
        nullptr, nullptr, nullptr, out, 0);
  } else {
    bf16* qw = (bf16*)d_ws;
    bf16* kw = qw + M4;
    bf16* vw = kw + M4;
    bf16* cw = vw + M4;
    gemm_kernel<float, float, 128><<<dim3(32, 24), 256, 0, stream>>>(
        x, Wq, Wk, Wv, qs, ks, vs, qw, kw, vw, nullptr, 1);
    attn_kernel<<<512, 256, 0, stream>>>(qw, kw, vw, cw);
    gemm_kernel<bf16, float, 64><<<dim3(32, 16), 256, 0, stream>>>(
        cw, Wo, nullptr, nullptr, os, nullptr, nullptr,
        nullptr, nullptr, nullptr, out, 0);
  }
}

// Round 10
// 190.466 us; speedup vs baseline: 1.0624x; 1.0624x over previous
//
#include <hip/hip_runtime.h>
#include <hip/hip_bf16.h>
#include <stdint.h>

// B=2, S=2048, D=1024, H=16, Hd=64.  Inputs/outputs FP32; internal bf16 MFMA.
// R10 = R8 config (2-barrier single-buffer loops everywhere; R9's dbuf
// regressed both attn and gemm) + attn wave split 2x2 (wq x wk): each wave
// does 64 queries x 32 keys per tile -> kf/vf LDS reads halve, mt-ILP
// doubles.  One-time cross-wave O/l reduction in epilogue via LDS.

typedef __bf16 bf16;
typedef __attribute__((ext_vector_type(8))) __bf16 bf16x8;
typedef __attribute__((ext_vector_type(4))) __bf16 bf16x4;
typedef __attribute__((ext_vector_type(4))) float f32x4;

#define DEVI __device__ __forceinline__

DEVI void gl_lds16(const void* g, void* l) {
  __builtin_amdgcn_global_load_lds(
      (const __attribute__((address_space(1))) void*)g,
      (__attribute__((address_space(3))) void*)l, 16, 0, 0);
}

DEVI bf16x8 load8(const bf16* p) { return *(const bf16x8*)p; }
DEVI bf16x8 load8(const float* p) {
  f32x4 a = *(const f32x4*)p;
  f32x4 b = *(const f32x4*)(p + 4);
  bf16x8 r;
  r[0] = (bf16)a[0]; r[1] = (bf16)a[1]; r[2] = (bf16)a[2]; r[3] = (bf16)a[3];
  r[4] = (bf16)b[0]; r[5] = (bf16)b[1]; r[6] = (bf16)b[2]; r[7] = (bf16)b[3];
  return r;
}

// ---------------------------------------------------------------------------
// fp32 -> bf16 bulk convert.  grid (512, 8): y<4 -> W[y], y>=4 -> x quarter.
// ---------------------------------------------------------------------------
__global__ __launch_bounds__(256)
void cvt_kernel(const float* __restrict__ x,
                const float* __restrict__ w0, const float* __restrict__ w1,
                const float* __restrict__ w2, const float* __restrict__ w3,
                bf16* __restrict__ xb, bf16* __restrict__ wb) {
  const int y = blockIdx.y;
  const float* src;
  bf16* dst;
  if (y < 4) {
    src = (y == 0) ? w0 : (y == 1) ? w1 : (y == 2) ? w2 : w3;
    dst = wb + (size_t)y * 1048576;
  } else {
    src = x + (size_t)(y - 4) * 1048576;
    dst = xb + (size_t)(y - 4) * 1048576;
  }
  const int i = (blockIdx.x * 256 + threadIdx.x) * 8;
  *(bf16x8*)(dst + i) = load8(src + i);
}

// ---------------------------------------------------------------------------
// GEMM (R8-exact): C[m,n] = (sum_k X[m,k]*W[n,k]) * scale[n] [*emul].
// bf16 operands stage via global_load_lds (src-swizzled); fp32 manual.
// three=1 (NTILE=128): 8 n-tiles per W; Q/K -> [B,H,S,64] (Q gets
//   emul=0.125*log2e), V -> transposed [B,H,64,S].
// three=0 (NTILE=64): plain fp32 row-major out.
// ---------------------------------------------------------------------------
template <typename XT, typename WT, int NTILE>
__global__ __launch_bounds__(256, 2)
void gemm_kernel(const XT* __restrict__ X,
                 const WT* __restrict__ W0, const WT* __restrict__ W1,
                 const WT* __restrict__ W2,
                 const float* __restrict__ s0, const float* __restrict__ s1,
                 const float* __restrict__ s2,
                 bf16* __restrict__ o0, bf16* __restrict__ o1,
                 bf16* __restrict__ o2, float* __restrict__ ofp, int three) {
  constexpr int NF = NTILE / 32;
  constexpr bool ASYNC_A = (sizeof(XT) == 2);
  constexpr bool ASYNC_B = (sizeof(WT) == 2);
  __shared__ bf16 As[128 * 32];
  __shared__ bf16 Bs[NTILE * 32];

  const int t = threadIdx.x;
  const int lane = t & 63;
  const int w = t >> 6;
  const int wm = w >> 1, wn = w & 1;
  const int m0 = blockIdx.x * 128;
  const int cl = lane & 15, quad = lane >> 4;

  const WT* Wp; const float* sp; bf16* op; int mode, n0; float emul = 1.f;
  if (three) {
    int which = blockIdx.y >> 3;
    n0 = (blockIdx.y & 7) * 128;
    if (which == 0)      { Wp = W0; sp = s0; op = o0; mode = 1; emul = 0.18033688f; }
    else if (which == 1) { Wp = W1; sp = s1; op = o1; mode = 1; }
    else                 { Wp = W2; sp = s2; op = o2; mode = 2; }
  } else {
    n0 = blockIdx.y * NTILE; Wp = W0; sp = s0; op = o0; mode = 0;
  }

  f32x4 zero = {0.f, 0.f, 0.f, 0.f};
  f32x4 acc[4][NF];
#pragma unroll
  for (int i = 0; i < 4; i++)
#pragma unroll
    for (int j = 0; j < NF; j++) acc[i][j] = zero;

  const int srow = t >> 2;
  const int gcol_sw = ((t & 3) ^ (srow & 3)) * 8;
  const int gcol = (t & 3) * 8;
  const int sphys = (((t & 3) ^ (srow & 3)) << 3);

  for (int k0 = 0; k0 < 1024; k0 += 32) {
    bf16x8 a0, a1, b0, b1;
    if constexpr (!ASYNC_A) {
      a0 = load8(&X[(uint64_t)(m0 + srow) * 1024 + k0 + gcol]);
      a1 = load8(&X[(uint64_t)(m0 + 64 + srow) * 1024 + k0 + gcol]);
    }
    if constexpr (!ASYNC_B) {
      b0 = load8(&Wp[(uint64_t)(n0 + srow) * 1024 + k0 + gcol]);
      if constexpr (NTILE == 128)
        b1 = load8(&Wp[(uint64_t)(n0 + 64 + srow) * 1024 + k0 + gcol]);
    }
    __syncthreads();
    if constexpr (ASYNC_A) {
      gl_lds16(X + (uint64_t)(m0 + srow) * 1024 + k0 + gcol_sw, (char*)As + t * 16);
      gl_lds16(X + (uint64_t)(m0 + 64 + srow) * 1024 + k0 + gcol_sw,
               (char*)As + 4096 + t * 16);
    } else {
      *(bf16x8*)&As[srow * 32 + sphys] = a0;
      *(bf16x8*)&As[(64 + srow) * 32 + sphys] = a1;
    }
    if constexpr (ASYNC_B) {
      gl_lds16(Wp + (uint64_t)(n0 + srow) * 1024 + k0 + gcol_sw, (char*)Bs + t * 16);
      if constexpr (NTILE == 128)
        gl_lds16(Wp + (uint64_t)(n0 + 64 + srow) * 1024 + k0 + gcol_sw,
                 (char*)Bs + 4096 + t * 16);
    } else {
      *(bf16x8*)&Bs[srow * 32 + sphys] = b0;
      if constexpr (NTILE == 128)
        *(bf16x8*)&Bs[(64 + srow) * 32 + sphys] = b1;
    }
    __syncthreads();

    bf16x8 af[4], bfr[NF];
#pragma unroll
    for (int mt = 0; mt < 4; mt++) {
      const int row = wm * 64 + mt * 16 + cl;
      af[mt] = *(const bf16x8*)&As[row * 32 + ((quad ^ (cl & 3)) << 3)];
    }
#pragma unroll
    for (int nt = 0; nt < NF; nt++) {
      const int row = wn * (NF * 16) + nt * 16 + cl;
      bfr[nt] = *(const bf16x8*)&Bs[row * 32 + ((quad ^ (cl & 3)) << 3)];
    }
#pragma unroll
    for (int mt = 0; mt < 4; mt++)
#pragma unroll
      for (int nt = 0; nt < NF; nt++)
        acc[mt][nt] = __builtin_amdgcn_mfma_f32_16x16x32_bf16(af[mt], bfr[nt],
                                                              acc[mt][nt], 0, 0, 0);
  }

#pragma unroll
  for (int nt = 0; nt < NF; nt++) {
    const int gn = n0 + wn * (NF * 16) + nt * 16 + cl;
    const float sc = sp[gn] * emul;
#pragma unroll
    for (int mt = 0; mt < 4; mt++) {
      const int gmb = m0 + wm * 64 + mt * 16 + quad * 4;
#pragma unroll
      for (int r = 0; r < 4; r++) {
        const int gm = gmb + r;
        const float v = acc[mt][nt][r] * sc;
        if (mode == 0) {
          ofp[(uint64_t)gm * 1024 + gn] = v;
        } else {
          const int b = gm >> 11, s = gm & 2047;
          const int h = gn >> 6, hd = gn & 63;
          uint64_t addr;
          if (mode == 1) addr = ((uint64_t)(b * 16 + h) * 2048 + s) * 64 + hd;
          else           addr = ((uint64_t)(b * 16 + h) * 64 + hd) * 2048 + s;
          op[addr] = (bf16)v;
        }
      }
    }
  }
}

// ---------------------------------------------------------------------------
// Flash attention v4: wave split 2x2.  1D grid 512 blocks, XCD-swizzled:
// xcd=id&7, k=id>>3, bh=xcd*4+(k>>4), qt=k&15, q0=qt*128.
// Wave (wq=w>>1, wk=w&1): queries q0+wq*64+mt*16+cl (mt=0..3), keys
// wk*32+[0,32) of each 64-key tile.  S^T = mfma(K,Q) K=64; exp2 -> bf16x4
// -> b64 into per-wave P[64q][32k] (8B-unit swizzle u^(cl&6), bit0 kept so
// b128 reads stay aligned) -> one K=32 PV mfma per (mt,nt).
// Epilogue: cross-wave (wk) O+l reduction via LDS, then store.
// ---------------------------------------------------------------------------
__global__ __launch_bounds__(256, 2)
void attn_kernel(const bf16* __restrict__ Qw, const bf16* __restrict__ Kw,
                 const bf16* __restrict__ Vtw, bf16* __restrict__ Ctx) {
  __shared__ bf16 Ks[64 * 64];          // [key][d], chunk c^(key&7)    (8 KB)
  __shared__ bf16 Vs[64 * 64];          // [hd][key], chunk c^(hd&7)    (8 KB)
  __shared__ bf16 Ps[4][64 * 32];       // per-wave P[q][k]             (16 KB)
  __shared__ float Lbuf[4 * 64];        //                              (1 KB)
  __shared__ float Obuf[2][4096];       // per-wq partial O             (32 KB)

  const int t = threadIdx.x, lane = t & 63, w = t >> 6;
  const int cl = lane & 15, quad = lane >> 4;
  const int wq = w >> 1, wk = w & 1;

  const int id = blockIdx.x;
  const int xcd = id & 7, kk = id >> 3;
  const int bh = xcd * 4 + (kk >> 4);
  const int qt = kk & 15;
  const int b = bh >> 4, h = bh & 15;
  const int q0 = qt * 128;

  const bf16* Qh = Qw + (uint64_t)bh * 2048 * 64;
  const bf16* Kh = Kw + (uint64_t)bh * 2048 * 64;
  const bf16* Vh = Vtw + (uint64_t)bh * 64 * 2048;

  // Q B-fragments: B[k=h*32+quad*8+j][n=cl], queries wq*64+mt*16+cl
  bf16x8 qf[4][2];
#pragma unroll
  for (int mt = 0; mt < 4; mt++) {
    const int r = q0 + wq * 64 + mt * 16 + cl;
    qf[mt][0] = *(const bf16x8*)&Qh[(uint64_t)r * 64 + quad * 8];
    qf[mt][1] = *(const bf16x8*)&Qh[(uint64_t)r * 64 + 32 + quad * 8];
  }

  f32x4 zero = {0.f, 0.f, 0.f, 0.f};
  f32x4 o_acc[4][4];
  float lsum[4] = {0.f, 0.f, 0.f, 0.f};
#pragma unroll
  for (int mt = 0; mt < 4; mt++)
#pragma unroll
    for (int nt = 0; nt < 4; nt++) o_acc[mt][nt] = zero;

  const int srow = t >> 3;                         // 0..31
  const int gcol_sw = ((t & 7) ^ (srow & 7)) * 8;  // swizzled source col
  bf16* Pw = Ps[w];

  for (int k0 = 0; k0 < 2048; k0 += 64) {
    __syncthreads();
    gl_lds16(Kh + (uint64_t)(k0 + srow) * 64 + gcol_sw,        (char*)Ks + t * 16);
    gl_lds16(Kh + (uint64_t)(k0 + 32 + srow) * 64 + gcol_sw,   (char*)Ks + 4096 + t * 16);
    gl_lds16(Vh + (uint64_t)srow * 2048 + k0 + gcol_sw,        (char*)Vs + t * 16);
    gl_lds16(Vh + (uint64_t)(32 + srow) * 2048 + k0 + gcol_sw, (char*)Vs + 4096 + t * 16);
    __syncthreads();   // tiles resident

    // K A-frags for this wave's 32-key half
    bf16x8 kf[2][2];
#pragma unroll
    for (int knt = 0; knt < 2; knt++) {
      const int krow = wk * 32 + knt * 16 + cl;
#pragma unroll
      for (int hh = 0; hh < 2; hh++)
        kf[knt][hh] = *(const bf16x8*)&Ks[krow * 64 +
                                          (((hh * 4 + quad) ^ (cl & 7)) << 3)];
    }
    // V B-frags (K=32): rows nt*16+cl, keys wk*32+quad*8+[0,8)
    bf16x8 vf[4];
#pragma unroll
    for (int nt = 0; nt < 4; nt++)
      vf[nt] = *(const bf16x8*)&Vs[(nt * 16 + cl) * 64 +
                                   (((wk * 4 + quad) ^ (cl & 7)) << 3)];

    // S^T (log2 units) -> exp2 -> P (per-wave LDS)
#pragma unroll
    for (int mt = 0; mt < 4; mt++) {
#pragma unroll
      for (int knt = 0; knt < 2; knt++) {
        f32x4 s = __builtin_amdgcn_mfma_f32_16x16x32_bf16(kf[knt][0], qf[mt][0],
                                                          zero, 0, 0, 0);
        s = __builtin_amdgcn_mfma_f32_16x16x32_bf16(kf[knt][1], qf[mt][1], s, 0, 0, 0);
        bf16x4 pk;
        float ls = 0.f;
#pragma unroll
        for (int r = 0; r < 4; r++) {
          const float p = __builtin_amdgcn_exp2f(s[r]);
          ls += p;
          pk[r] = (bf16)p;
        }
        lsum[mt] += ls;
        const int row = mt * 16 + cl;
        const int u = knt * 4 + quad;               // 8B unit (4 keys)
        *(bf16x4*)&Pw[row * 32 + ((u ^ (cl & 6)) << 2)] = pk;
      }
    }

    // P A-frags (K=32, all 32 keys) + PV
#pragma unroll
    for (int mt = 0; mt < 4; mt++) {
      const int row = mt * 16 + cl;
      bf16x8 pf = *(const bf16x8*)&Pw[row * 32 + (((2 * quad) ^ (cl & 6)) << 2)];
#pragma unroll
      for (int nt = 0; nt < 4; nt++)
        o_acc[mt][nt] = __builtin_amdgcn_mfma_f32_16x16x32_bf16(pf, vf[nt],
                                                                o_acc[mt][nt], 0, 0, 0);
    }
  }

  // ---- epilogue: per-wave l reduce, then cross-wk O/l combine ----
#pragma unroll
  for (int mt = 0; mt < 4; mt++) {
    float l = lsum[mt];
    l += __shfl_xor(l, 16);
    l += __shfl_xor(l, 32);
    if (lane < 16) Lbuf[w * 64 + mt * 16 + lane] = l;
  }
  __syncthreads();
  if (wk == 1) {
#pragma unroll
    for (int mt = 0; mt < 4; mt++)
#pragma unroll
      for (int nt = 0; nt < 4; nt++)
        *(f32x4*)&Obuf[wq][(mt * 4 + nt) * 256 + lane * 4] = o_acc[mt][nt];
  }
  __syncthreads();
  if (wk == 0) {
#pragma unroll
    for (int mt = 0; mt < 4; mt++) {
      float linv[4];
#pragma unroll
      for (int r = 0; r < 4; r++) {
        const int ql = mt * 16 + quad * 4 + r;
        linv[r] = 1.0f / (Lbuf[(wq * 2) * 64 + ql] + Lbuf[(wq * 2 + 1) * 64 + ql]);
      }
#pragma unroll
      for (int nt = 0; nt < 4; nt++) {
        f32x4 other = *(const f32x4*)&Obuf[wq][(mt * 4 + nt) * 256 + lane * 4];
#pragma unroll
        for (int r = 0; r < 4; r++) {
          const int q = q0 + wq * 64 + mt * 16 + quad * 4 + r;
          const int hd = nt * 16 + cl;
          Ctx[(uint64_t)(b * 2048 + q) * 1024 + h * 64 + hd] =
              (bf16)((o_acc[mt][nt][r] + other[r]) * linv[r]);
        }
      }
    }
  }
}

// ---------------------------------------------------------------------------
extern "C" void kernel_launch(void* const* d_in, const int* in_sizes, int n_in,
                              void* d_out, int out_size, void* d_ws, size_t ws_size,
                              hipStream_t stream) {
  const float* x  = (const float*)d_in[0];
  const float* Wq = (const float*)d_in[1];
  const float* Wk = (const float*)d_in[2];
  const float* Wv = (const float*)d_in[3];
  const float* Wo = (const float*)d_in[4];
  const float* qs = (const float*)d_in[5];
  const float* ks = (const float*)d_in[6];
  const float* vs = (const float*)d_in[7];
  const float* os = (const float*)d_in[8];
  float* out = (float*)d_out;

  const size_t M4 = 4194304, M1 = 1048576;

  if (ws_size >= (size_t)40 * 1024 * 1024) {
    bf16* xb = (bf16*)d_ws;        // 4M bf16; reused as cw after QKV
    bf16* wb = xb + M4;            // wq|wk|wv|wo
    bf16* qw = wb + M4;
    bf16* kw = qw + M4;
    bf16* vw = kw + M4;
    bf16* cw = xb;

    cvt_kernel<<<dim3(512, 8), 256, 0, stream>>>(x, Wq, Wk, Wv, Wo, xb, wb);
    gemm_kernel<bf16, bf16, 128><<<dim3(32, 24), 256, 0, stream>>>(
        xb, wb, wb + M1, wb + 2 * M1, qs, ks, vs, qw, kw, vw, nullptr, 1);
    attn_kernel<<<512, 256, 0, stream>>>(qw, kw, vw, cw);
    gemm_kernel<bf16, bf16, 64><<<dim3(32, 16), 256, 0, stream>>>(
        cw, wb + 3 * M1, nullptr, nullptr, os, nullptr, nullptr,
        nullptr, nullptr, nullptr, out, 0);
  } else {
    bf16* qw = (bf16*)d_ws;
    bf16* kw = qw + M4;
    bf16* vw = kw + M4;
    bf16* cw = vw + M4;
    gemm_kernel<float, float, 128><<<dim3(32, 24), 256, 0, stream>>>(
        x, Wq, Wk, Wv, qs, ks, vs, qw, kw, vw, nullptr, 1);
    attn_kernel<<<512, 256, 0, stream>>>(qw, kw, vw, cw);
    gemm_kernel<bf16, float, 64><<<dim3(32, 16), 256, 0, stream>>>(
        cw, Wo, nullptr, nullptr, os, nullptr, nullptr,
        nullptr, nullptr, nullptr, out, 0);
  }
}